// Round 2
// baseline (994.149 us; speedup 1.0000x reference)
//
#include <hip/hip_runtime.h>

typedef unsigned short u16;
typedef __attribute__((ext_vector_type(8))) short short8;
typedef __attribute__((ext_vector_type(4))) float f32x4;

#define NB 32768

__device__ __forceinline__ u16 f2bf(float x){
  unsigned int u = __float_as_uint(x);
  u += 0x7fffu + ((u >> 16) & 1u);
  return (u16)(u >> 16);
}
__device__ __forceinline__ float bf2f(short h){
  return __uint_as_float(((unsigned int)(u16)h) << 16);
}
__device__ __forceinline__ short8 pack8(float4 a, float4 b){
  short8 p;
  p[0]=(short)f2bf(a.x); p[1]=(short)f2bf(a.y); p[2]=(short)f2bf(a.z); p[3]=(short)f2bf(a.w);
  p[4]=(short)f2bf(b.x); p[5]=(short)f2bf(b.y); p[6]=(short)f2bf(b.z); p[7]=(short)f2bf(b.w);
  return p;
}

// ---------------- K0: weight convert/transpose to bf16 [N][K] ----------------
__global__ __launch_bounds__(256) void k0_conv(
    const float* __restrict__ Wenc, const float* __restrict__ Wsenc,
    const float* __restrict__ Wk, const float* __restrict__ Wsel, const float* __restrict__ Wv,
    const float* __restrict__ Wc1, const float* __restrict__ Wc2,
    u16* __restrict__ WencB, u16* __restrict__ WsencB,
    u16* __restrict__ WkB, u16* __restrict__ WvB, u16* __restrict__ WselB,
    u16* __restrict__ Wc1B, u16* __restrict__ Wc2B)
{
  int idx = blockIdx.x * 256 + threadIdx.x;
  if (idx < 307200){                       // WencB[a][n<128][k<160] = Wenc[a][k][n]
    int a = idx / 20480, r = idx % 20480, n = r / 160, k = r % 160;
    WencB[idx] = f2bf(Wenc[a*20480 + k*128 + n]);
  } else if (idx < 552960){                // WsencB[a][n][k] 128x128
    int i = idx - 307200; int a = i / 16384, r = i % 16384, n = r / 128, k = r % 128;
    WsencB[i] = f2bf(Wsenc[a*16384 + k*128 + n]);
  } else if (idx < 569344){                // WkB[c=nh*32+d][k<128] = Wk[nh][k][d]
    int i = idx - 552960; int c = i / 128, k = i % 128;
    WkB[i] = f2bf(Wk[(c>>5)*4096 + k*32 + (c&31)]);
  } else if (idx < 585728){
    int i = idx - 569344; int c = i / 128, k = i % 128;
    WvB[i] = f2bf(Wv[(c>>5)*4096 + k*32 + (c&31)]);
  } else if (idx < 602112){
    int i = idx - 585728; int c = i / 128, k = i % 128;
    WselB[i] = f2bf(Wsel[(c>>5)*4096 + k*32 + (c&31)]);
  } else if (idx < 1093632){               // Wc1B[a][n<128][k<256] = Wc1[a][k][n]
    int i = idx - 602112; int a = i / 32768, r = i % 32768, n = r / 256, k = r % 256;
    Wc1B[i] = f2bf(Wc1[a*32768 + k*128 + n]);
  } else if (idx < 1155072){               // Wc2B[a][n<32][k<128] = Wc2[a][k][n]
    int i = idx - 1093632; int a = i / 4096, r = i % 4096, n = r / 128, k = r % 128;
    Wc2B[i] = f2bf(Wc2[a*4096 + k*32 + n]);
  }
}

// ---------------- fused main kernel ----------------
// Block = 16 batch rows x all 15 agents. 1024 threads = 16 waves.
// LDS regions (byte offsets):
//   R1 @ 0      : 61440  SA (sa_enc)  [240 rows][256B] swizzled
//   R2 @ 61440  : 61440  S -> SE -> hidden h   [240][256B] swizzled
//   R3 @ 122880 : 30720  P1(15360: K_h -> attn_h) | P2(15360: sel_h -> V_h); later out f32 bounce
#define R1 0
#define R2 61440
#define P1 122880
#define P2 138240
#define R3 122880
#define K_LDS 153600

__device__ __forceinline__ short8 ldA(const char* lds, int off, int row, int slot){
  return *(const short8*)(lds + off + row*256 + ((slot ^ (row & 7)) << 4));
}
__device__ __forceinline__ void stSwz(char* lds, int off, int row, int col, u16 v){
  *(u16*)(lds + off + row*256 + ((((col>>3) ^ (row&7))) << 4) + ((col&7) << 1)) = v;
}

#define MFMA(a8,b8,c) __builtin_amdgcn_mfma_f32_16x16x32_bf16(a8, b8, c, 0, 0, 0)

__global__ __launch_bounds__(1024) void k_fused(
    const float* __restrict__ states, const float* __restrict__ actions,
    const float* __restrict__ benc, const float* __restrict__ bsenc, const float* __restrict__ bvp,
    const float* __restrict__ bc1, const float* __restrict__ bc2,
    const u16* __restrict__ WencB, const u16* __restrict__ WsencB,
    const u16* __restrict__ WkB, const u16* __restrict__ WvB, const u16* __restrict__ WselB,
    const u16* __restrict__ Wc1B, const u16* __restrict__ Wc2B,
    float* __restrict__ outp)
{
  extern __shared__ __align__(16) char lds[];
  const int b0 = blockIdx.x * 16;
  const int t = threadIdx.x;
  const int lane = t & 63, w = t >> 6;
  const int l15 = lane & 15, l4 = lane >> 4;

  // ---- stage states -> R2 (bf16 swizzled, 240 rows x 256B) ----
  for (int c = t; c < 3840; c += 1024){
    int row = c >> 4, cb = c & 15;
    int ag = row >> 4, br = row & 15;
    const float* sp = states + ((size_t)ag*NB + b0 + br)*128 + cb*8;
    float4 v0 = *(const float4*)sp, v1 = *(const float4*)(sp + 4);
    *(short8*)(lds + R2 + row*256 + ((cb ^ (row&7)) << 4)) = pack8(v0, v1);
  }
  __syncthreads();

  // ---- phase E: SA (sa_enc -> R1) + SE accs (in regs) ----
  #pragma unroll
  for (int uu = 0; uu < 2; ++uu){
    const int u = w + uu*16;
    if (u < 30){
      const int a = u >> 1, nh = u & 1;
      f32x4 acc[4];
      #pragma unroll
      for (int fn = 0; fn < 4; ++fn) acc[fn] = (f32x4)0.0f;
      const u16* Wb = WencB + (size_t)a*20480 + (size_t)(nh*64)*160;
      for (int ks = 0; ks < 4; ++ks){
        short8 a8 = ldA(lds, R2, a*16 + l15, ks*4 + l4);
        #pragma unroll
        for (int fn = 0; fn < 4; ++fn){
          short8 b8 = *(const short8*)(Wb + (fn*16 + l15)*160 + ks*32 + l4*8);
          acc[fn] = MFMA(a8, b8, acc[fn]);
        }
      }
      { // K tail 128..159 from actions (fp32 direct from global)
        const float* ap = actions + ((size_t)a*NB + b0 + l15)*32 + l4*8;
        float4 u0 = *(const float4*)ap, u1 = *(const float4*)(ap + 4);
        short8 a8 = pack8(u0, u1);
        #pragma unroll
        for (int fn = 0; fn < 4; ++fn){
          short8 b8 = *(const short8*)(Wb + (fn*16 + l15)*160 + 128 + l4*8);
          acc[fn] = MFMA(a8, b8, acc[fn]);
        }
      }
      #pragma unroll
      for (int fn = 0; fn < 4; ++fn){
        int col = nh*64 + fn*16 + l15;
        float bb = benc[a*128 + col];
        #pragma unroll
        for (int q = 0; q < 4; ++q){
          int row = a*16 + l4*4 + q;
          float v = acc[fn][q] + bb; v = v > 0.f ? v : 0.01f*v;
          stSwz(lds, R1, row, col, f2bf(v));
        }
      }
    }
  }
  // SE accumulators (held across the barrier, then overwrite R2)
  f32x4 seacc[2][4];
  #pragma unroll
  for (int uu = 0; uu < 2; ++uu)
    #pragma unroll
    for (int fn = 0; fn < 4; ++fn) seacc[uu][fn] = (f32x4)0.0f;
  #pragma unroll
  for (int uu = 0; uu < 2; ++uu){
    const int u = w + uu*16;
    if (u < 30){
      const int a = u >> 1, nh = u & 1;
      const u16* Wb = WsencB + (size_t)a*16384 + (size_t)(nh*64)*128;
      for (int ks = 0; ks < 4; ++ks){
        short8 a8 = ldA(lds, R2, a*16 + l15, ks*4 + l4);
        #pragma unroll
        for (int fn = 0; fn < 4; ++fn){
          short8 b8 = *(const short8*)(Wb + (fn*16 + l15)*128 + ks*32 + l4*8);
          seacc[uu][fn] = MFMA(a8, b8, seacc[uu][fn]);
        }
      }
    }
  }
  __syncthreads();
  // SE store over R2
  #pragma unroll
  for (int uu = 0; uu < 2; ++uu){
    const int u = w + uu*16;
    if (u < 30){
      const int a = u >> 1, nh = u & 1;
      #pragma unroll
      for (int fn = 0; fn < 4; ++fn){
        int col = nh*64 + fn*16 + l15;
        float bb = bsenc[a*128 + col];
        #pragma unroll
        for (int q = 0; q < 4; ++q){
          int row = a*16 + l4*4 + q;
          float v = seacc[uu][fn][q] + bb; v = v > 0.f ? v : 0.01f*v;
          stSwz(lds, R2, row, col, f2bf(v));
        }
      }
    }
  }
  __syncthreads();

  // ---- critic GEMM1 part-s: acc_c1 += SE @ Wc1[0:128,:]  (persistent regs) ----
  f32x4 c1[8];
  #pragma unroll
  for (int fn = 0; fn < 8; ++fn) c1[fn] = (f32x4)0.0f;
  if (w < 15){
    for (int ks = 0; ks < 4; ++ks){
      short8 a8 = ldA(lds, R2, w*16 + l15, ks*4 + l4);
      #pragma unroll
      for (int fn = 0; fn < 8; ++fn){
        short8 b8 = *(const short8*)(Wc1B + (size_t)w*32768 + (fn*16 + l15)*256 + ks*32 + l4*8);
        c1[fn] = MFMA(a8, b8, c1[fn]);
      }
    }
  }

  // ---- head loop ----
  for (int h = 0; h < 4; ++h){
    float pb[15]; float inv = 0.f;
    // a: sel_h -> P2 (from SE/R2), K_h -> P1 (from SA/R1)
    #pragma unroll
    for (int uu = 0; uu < 2; ++uu){
      const int u = w + uu*16;
      if (u < 30){
        const int m = u >> 1, nf = u & 1;
        f32x4 as = (f32x4)0.0f, ak = (f32x4)0.0f;
        const int nrow = h*32 + nf*16 + l15;
        for (int ks = 0; ks < 4; ++ks){
          short8 a2 = ldA(lds, R2, m*16 + l15, ks*4 + l4);
          short8 a1 = ldA(lds, R1, m*16 + l15, ks*4 + l4);
          short8 bs = *(const short8*)(WselB + (size_t)nrow*128 + ks*32 + l4*8);
          short8 bk = *(const short8*)(WkB   + (size_t)nrow*128 + ks*32 + l4*8);
          as = MFMA(a2, bs, as);
          ak = MFMA(a1, bk, ak);
        }
        #pragma unroll
        for (int q = 0; q < 4; ++q){
          int row = m*16 + l4*4 + q, col = nf*16 + l15;
          *(u16*)(lds + P2 + row*64 + col*2) = f2bf(as[q]);
          *(u16*)(lds + P1 + row*64 + col*2) = f2bf(ak[q]);
        }
      }
    }
    __syncthreads();
    // b: logits + softmax (wave w = query agent; 4 lanes per (i,b) unit)
    if (w < 15){
      const int bq = lane >> 2, l = lane & 3;
      const int qrow = w*16 + bq;
      short8 s8 = *(const short8*)(lds + P2 + qrow*64 + l*16);
      float sf[8];
      #pragma unroll
      for (int x = 0; x < 8; ++x) sf[x] = bf2f(s8[x]);
      #pragma unroll
      for (int j = 0; j < 15; ++j){
        short8 k8 = *(const short8*)(lds + P1 + (j*16 + bq)*64 + l*16);
        float d = 0.f;
        #pragma unroll
        for (int x = 0; x < 8; ++x) d += bf2f(k8[x]) * sf[x];
        d += __shfl_xor(d, 1);
        d += __shfl_xor(d, 2);
        pb[j] = d * 0.17677669529663687f;
      }
      float mx = -1e30f;
      #pragma unroll
      for (int j = 0; j < 15; ++j) if (j != w) mx = fmaxf(mx, pb[j]);
      float sum = 0.f;
      #pragma unroll
      for (int j = 0; j < 15; ++j){
        float p = (j == w) ? 0.f : __expf(pb[j] - mx);
        pb[j] = p; sum += p;
      }
      inv = 1.f / sum;
    }
    __syncthreads();
    // c: V_h -> P2 (over sel, dead)
    #pragma unroll
    for (int uu = 0; uu < 2; ++uu){
      const int u = w + uu*16;
      if (u < 30){
        const int m = u >> 1, nf = u & 1;
        f32x4 av = (f32x4)0.0f;
        const int nrow = h*32 + nf*16 + l15;
        for (int ks = 0; ks < 4; ++ks){
          short8 a1 = ldA(lds, R1, m*16 + l15, ks*4 + l4);
          short8 b8 = *(const short8*)(WvB + (size_t)nrow*128 + ks*32 + l4*8);
          av = MFMA(a1, b8, av);
        }
        int col = nf*16 + l15;
        float bb = bvp[h*32 + col];
        #pragma unroll
        for (int q = 0; q < 4; ++q){
          int row = m*16 + l4*4 + q;
          float v = av[q] + bb; v = v > 0.f ? v : 0.01f*v;
          *(u16*)(lds + P2 + row*64 + col*2) = f2bf(v);
        }
      }
    }
    __syncthreads();
    // d: PV (probs @ V) -> attn slice -> P1 (over K, dead)
    if (w < 15){
      const int bq = lane >> 2, l = lane & 3;
      const int qrow = w*16 + bq;
      float oa[8];
      #pragma unroll
      for (int x = 0; x < 8; ++x) oa[x] = 0.f;
      #pragma unroll
      for (int j = 0; j < 15; ++j){
        if (j == w) continue;
        float p = pb[j];
        short8 v8 = *(const short8*)(lds + P2 + (j*16 + bq)*64 + l*16);
        #pragma unroll
        for (int x = 0; x < 8; ++x) oa[x] += p * bf2f(v8[x]);
      }
      short8 o;
      #pragma unroll
      for (int x = 0; x < 8; ++x) o[x] = (short)f2bf(oa[x] * inv);
      *(short8*)(lds + P1 + qrow*64 + l*16) = o;
    }
    __syncthreads();
    // e: acc_c1 += attn_h @ Wc1[128+32h : 160+32h, :]   (K=32, one kstep)
    if (w < 15){
      short8 a8 = *(const short8*)(lds + P1 + (w*16 + l15)*64 + l4*16);
      #pragma unroll
      for (int fn = 0; fn < 8; ++fn){
        short8 b8 = *(const short8*)(Wc1B + (size_t)w*32768 + (fn*16 + l15)*256 + 128 + h*32 + l4*8);
        c1[fn] = MFMA(a8, b8, c1[fn]);
      }
    }
    __syncthreads();
  }

  // ---- critic hidden: bias+lrelu -> R2 (over SE, dead) ----
  if (w < 15){
    #pragma unroll
    for (int fn = 0; fn < 8; ++fn){
      int col = fn*16 + l15;
      float bb = bc1[w*128 + col];
      #pragma unroll
      for (int q = 0; q < 4; ++q){
        int row = w*16 + l4*4 + q;
        float v = c1[fn][q] + bb; v = v > 0.f ? v : 0.01f*v;
        stSwz(lds, R2, row, col, f2bf(v));
      }
    }
  }
  __syncthreads();

  // ---- critic GEMM2: out = h @ Wc2 + bc2 -> R3 f32 bounce ----
  #pragma unroll
  for (int uu = 0; uu < 2; ++uu){
    const int u = w + uu*16;
    if (u < 30){
      const int m = u >> 1, nf = u & 1;
      f32x4 a2 = (f32x4)0.0f;
      for (int ks = 0; ks < 4; ++ks){
        short8 a8 = ldA(lds, R2, m*16 + l15, ks*4 + l4);
        short8 b8 = *(const short8*)(Wc2B + (size_t)m*4096 + (nf*16 + l15)*128 + ks*32 + l4*8);
        a2 = MFMA(a8, b8, a2);
      }
      int col = nf*16 + l15;
      float bb = bc2[m*32 + col];
      #pragma unroll
      for (int q = 0; q < 4; ++q){
        int row = m*16 + l4*4 + q;
        *(float*)(lds + R3 + row*128 + col*4) = a2[q] + bb;
      }
    }
  }
  __syncthreads();
  // coalesced copy out
  for (int e = t; e < 1920; e += 1024){
    f32x4 v = *(const f32x4*)(lds + R3 + e*16);
    int row = e >> 3, c4 = e & 7;
    *(f32x4*)(outp + ((size_t)(row >> 4)*NB + b0 + (row & 15))*32 + c4*4) = v;
  }
}

// ---------------- launch ----------------
extern "C" void kernel_launch(void* const* d_in, const int* in_sizes, int n_in,
                              void* d_out, int out_size, void* d_ws, size_t ws_size,
                              hipStream_t stream)
{
  const float* states  = (const float*)d_in[0];
  const float* actions = (const float*)d_in[1];
  const float* Wenc    = (const float*)d_in[2];
  const float* benc    = (const float*)d_in[3];
  const float* Wsenc   = (const float*)d_in[4];
  const float* bsenc   = (const float*)d_in[5];
  const float* Wk      = (const float*)d_in[6];
  const float* Wsel    = (const float*)d_in[7];
  const float* Wv      = (const float*)d_in[8];
  const float* bv      = (const float*)d_in[9];
  const float* Wc1     = (const float*)d_in[10];
  const float* bc1     = (const float*)d_in[11];
  const float* Wc2     = (const float*)d_in[12];
  const float* bc2     = (const float*)d_in[13];

  char* ws = (char*)d_ws;
  u16* WencB  = (u16*)(ws + 0);
  u16* WsencB = (u16*)(ws + 614400);
  u16* WkB    = (u16*)(ws + 1105920);
  u16* WvB    = (u16*)(ws + 1138688);
  u16* WselB  = (u16*)(ws + 1171456);
  u16* Wc1B   = (u16*)(ws + 1204224);
  u16* Wc2B   = (u16*)(ws + 2187264);
  if (ws_size < 2310144ULL) return;

  hipFuncSetAttribute((const void*)k_fused, hipFuncAttributeMaxDynamicSharedMemorySize, K_LDS);

  k0_conv<<<4512, 256, 0, stream>>>(Wenc, Wsenc, Wk, Wsel, Wv, Wc1, Wc2,
                                    WencB, WsencB, WkB, WvB, WselB, Wc1B, Wc2B);
  k_fused<<<2048, 1024, K_LDS, stream>>>(states, actions, benc, bsenc, bv, bc1, bc2,
                                         WencB, WsencB, WkB, WvB, WselB, Wc1B, Wc2B,
                                         (float*)d_out);
}

// Round 3
// 922.801 us; speedup vs baseline: 1.0773x; 1.0773x over previous
//
#include <hip/hip_runtime.h>

typedef unsigned short u16;
typedef __attribute__((ext_vector_type(8))) short short8;
typedef __attribute__((ext_vector_type(4))) float f32x4;

#define NB 32768

__device__ __forceinline__ u16 f2bf(float x){
  unsigned int u = __float_as_uint(x);
  u += 0x7fffu + ((u >> 16) & 1u);
  return (u16)(u >> 16);
}
__device__ __forceinline__ float bf2f(short h){
  return __uint_as_float(((unsigned int)(u16)h) << 16);
}
__device__ __forceinline__ short8 pack8(float4 a, float4 b){
  short8 p;
  p[0]=(short)f2bf(a.x); p[1]=(short)f2bf(a.y); p[2]=(short)f2bf(a.z); p[3]=(short)f2bf(a.w);
  p[4]=(short)f2bf(b.x); p[5]=(short)f2bf(b.y); p[6]=(short)f2bf(b.z); p[7]=(short)f2bf(b.w);
  return p;
}

// ---------------- K0: weight convert/transpose to bf16 [N][K] ----------------
__global__ __launch_bounds__(256) void k0_conv(
    const float* __restrict__ Wenc, const float* __restrict__ Wsenc,
    const float* __restrict__ Wk, const float* __restrict__ Wsel, const float* __restrict__ Wv,
    const float* __restrict__ Wc1, const float* __restrict__ Wc2,
    u16* __restrict__ WencB, u16* __restrict__ WsencB,
    u16* __restrict__ WkB, u16* __restrict__ WvB, u16* __restrict__ WselB,
    u16* __restrict__ Wc1B, u16* __restrict__ Wc2B)
{
  int idx = blockIdx.x * 256 + threadIdx.x;
  if (idx < 307200){                       // WencB[a][n<128][k<160] = Wenc[a][k][n]
    int a = idx / 20480, r = idx % 20480, n = r / 160, k = r % 160;
    WencB[idx] = f2bf(Wenc[a*20480 + k*128 + n]);
  } else if (idx < 552960){                // WsencB[a][n][k] 128x128
    int i = idx - 307200; int a = i / 16384, r = i % 16384, n = r / 128, k = r % 128;
    WsencB[i] = f2bf(Wsenc[a*16384 + k*128 + n]);
  } else if (idx < 569344){                // WkB[c=nh*32+d][k<128] = Wk[nh][k][d]
    int i = idx - 552960; int c = i / 128, k = i % 128;
    WkB[i] = f2bf(Wk[(c>>5)*4096 + k*32 + (c&31)]);
  } else if (idx < 585728){
    int i = idx - 569344; int c = i / 128, k = i % 128;
    WvB[i] = f2bf(Wv[(c>>5)*4096 + k*32 + (c&31)]);
  } else if (idx < 602112){
    int i = idx - 585728; int c = i / 128, k = i % 128;
    WselB[i] = f2bf(Wsel[(c>>5)*4096 + k*32 + (c&31)]);
  } else if (idx < 1093632){               // Wc1B[a][n<128][k<256] = Wc1[a][k][n]
    int i = idx - 602112; int a = i / 32768, r = i % 32768, n = r / 256, k = r % 256;
    Wc1B[i] = f2bf(Wc1[a*32768 + k*128 + n]);
  } else if (idx < 1155072){               // Wc2B[a][n<32][k<128] = Wc2[a][k][n]
    int i = idx - 1093632; int a = i / 4096, r = i % 4096, n = r / 128, k = r % 128;
    Wc2B[i] = f2bf(Wc2[a*4096 + k*32 + n]);
  }
}

// ---------------- fused main kernel ----------------
// Block = 16 batch rows x all 15 agents. 1024 threads = 16 waves, 1 block/CU.
// LDS regions (byte offsets):
//   R1 @ 0      : 61440  SA (sa_enc)  [240 rows][256B] swizzled
//   R2 @ 61440  : 61440  S -> SE -> hidden h   [240][256B] swizzled
//   R3 @ 122880 : 30720  P1(15360: actions -> K_h -> attn_h) | P2(15360: sel_h -> V_h); out f32 bounce
#define R1 0
#define R2 61440
#define P1 122880
#define P2 138240
#define R3 122880
#define K_LDS 153600

__device__ __forceinline__ short8 ldA(const char* lds, int off, int row, int slot){
  return *(const short8*)(lds + off + row*256 + ((slot ^ (row & 7)) << 4));
}
__device__ __forceinline__ void stSwz(char* lds, int off, int row, int col, u16 v){
  *(u16*)(lds + off + row*256 + ((((col>>3) ^ (row&7))) << 4) + ((col&7) << 1)) = v;
}

#define MFMA(a8,b8,c) __builtin_amdgcn_mfma_f32_16x16x32_bf16(a8, b8, c, 0, 0, 0)

__global__ __launch_bounds__(1024, 4) void k_fused(
    const float* __restrict__ states, const float* __restrict__ actions,
    const float* __restrict__ benc, const float* __restrict__ bsenc, const float* __restrict__ bvp,
    const float* __restrict__ bc1, const float* __restrict__ bc2,
    const u16* __restrict__ WencB, const u16* __restrict__ WsencB,
    const u16* __restrict__ WkB, const u16* __restrict__ WvB, const u16* __restrict__ WselB,
    const u16* __restrict__ Wc1B, const u16* __restrict__ Wc2B,
    float* __restrict__ outp)
{
  extern __shared__ __align__(16) char lds[];
  const int b0 = blockIdx.x * 16;
  const int t = threadIdx.x;
  const int lane = t & 63, w = t >> 6;
  const int l15 = lane & 15, l4 = lane >> 4;

  // ---- stage states -> R2 (bf16 swizzled, 240 rows x 256B) ----
  for (int c = t; c < 3840; c += 1024){
    int row = c >> 4, cb = c & 15;
    int ag = row >> 4, br = row & 15;
    const float* sp = states + ((size_t)ag*NB + b0 + br)*128 + cb*8;
    float4 v0 = *(const float4*)sp, v1 = *(const float4*)(sp + 4);
    *(short8*)(lds + R2 + row*256 + ((cb ^ (row&7)) << 4)) = pack8(v0, v1);
  }
  // ---- stage actions -> P1 (bf16 swizzled, 240 rows x 64B) ----
  if (t < 960){
    int row = t >> 2, sl = t & 3;
    int ag = row >> 4, br = row & 15;
    const float* ap = actions + ((size_t)ag*NB + b0 + br)*32 + sl*8;
    float4 v0 = *(const float4*)ap, v1 = *(const float4*)(ap + 4);
    *(short8*)(lds + P1 + row*64 + ((sl ^ (row&3)) << 4)) = pack8(v0, v1);
  }
  __syncthreads();

  // ---- phase E: SA (sa_enc -> R1) + SE accs (in regs) ----
  #pragma unroll
  for (int uu = 0; uu < 2; ++uu){
    const int u = w + uu*16;
    if (u < 30){
      const int a = u >> 1, nh = u & 1;
      f32x4 acc[4];
      #pragma unroll
      for (int fn = 0; fn < 4; ++fn) acc[fn] = (f32x4)0.0f;
      const u16* Wb = WencB + (size_t)a*20480 + (size_t)(nh*64)*160;
      for (int ks = 0; ks < 4; ++ks){
        short8 a8 = ldA(lds, R2, a*16 + l15, ks*4 + l4);
        #pragma unroll
        for (int fn = 0; fn < 4; ++fn){
          short8 b8 = *(const short8*)(Wb + (fn*16 + l15)*160 + ks*32 + l4*8);
          acc[fn] = MFMA(a8, b8, acc[fn]);
        }
      }
      { // K tail 128..159 from actions (staged in P1)
        int row = a*16 + l15;
        short8 a8 = *(const short8*)(lds + P1 + row*64 + ((l4 ^ (row&3)) << 4));
        #pragma unroll
        for (int fn = 0; fn < 4; ++fn){
          short8 b8 = *(const short8*)(Wb + (fn*16 + l15)*160 + 128 + l4*8);
          acc[fn] = MFMA(a8, b8, acc[fn]);
        }
      }
      #pragma unroll
      for (int fn = 0; fn < 4; ++fn){
        int col = nh*64 + fn*16 + l15;
        float bb = benc[a*128 + col];
        #pragma unroll
        for (int q = 0; q < 4; ++q){
          int row = a*16 + l4*4 + q;
          float v = acc[fn][q] + bb; v = v > 0.f ? v : 0.01f*v;
          stSwz(lds, R1, row, col, f2bf(v));
        }
      }
    }
  }
  // SE accumulators (held across the barrier, then overwrite R2)
  f32x4 seacc[2][4];
  #pragma unroll
  for (int uu = 0; uu < 2; ++uu)
    #pragma unroll
    for (int fn = 0; fn < 4; ++fn) seacc[uu][fn] = (f32x4)0.0f;
  #pragma unroll
  for (int uu = 0; uu < 2; ++uu){
    const int u = w + uu*16;
    if (u < 30){
      const int a = u >> 1, nh = u & 1;
      const u16* Wb = WsencB + (size_t)a*16384 + (size_t)(nh*64)*128;
      for (int ks = 0; ks < 4; ++ks){
        short8 a8 = ldA(lds, R2, a*16 + l15, ks*4 + l4);
        #pragma unroll
        for (int fn = 0; fn < 4; ++fn){
          short8 b8 = *(const short8*)(Wb + (fn*16 + l15)*128 + ks*32 + l4*8);
          seacc[uu][fn] = MFMA(a8, b8, seacc[uu][fn]);
        }
      }
    }
  }
  __syncthreads();
  // SE store over R2
  #pragma unroll
  for (int uu = 0; uu < 2; ++uu){
    const int u = w + uu*16;
    if (u < 30){
      const int a = u >> 1, nh = u & 1;
      #pragma unroll
      for (int fn = 0; fn < 4; ++fn){
        int col = nh*64 + fn*16 + l15;
        float bb = bsenc[a*128 + col];
        #pragma unroll
        for (int q = 0; q < 4; ++q){
          int row = a*16 + l4*4 + q;
          float v = seacc[uu][fn][q] + bb; v = v > 0.f ? v : 0.01f*v;
          stSwz(lds, R2, row, col, f2bf(v));
        }
      }
    }
  }
  __syncthreads();

  // ---- critic GEMM1 part-s: acc_c1 += SE @ Wc1[0:128,:]  (persistent regs) ----
  f32x4 c1[8];
  #pragma unroll
  for (int fn = 0; fn < 8; ++fn) c1[fn] = (f32x4)0.0f;
  if (w < 15){
    for (int ks = 0; ks < 4; ++ks){
      short8 a8 = ldA(lds, R2, w*16 + l15, ks*4 + l4);
      #pragma unroll
      for (int fn = 0; fn < 8; ++fn){
        short8 b8 = *(const short8*)(Wc1B + (size_t)w*32768 + (fn*16 + l15)*256 + ks*32 + l4*8);
        c1[fn] = MFMA(a8, b8, c1[fn]);
      }
    }
  }

  // ---- head loop ----
  for (int h = 0; h < 4; ++h){
    float pb[15]; float inv = 0.f;
    // a: sel_h -> P2 (from SE/R2), K_h -> P1 (from SA/R1)
    #pragma unroll
    for (int uu = 0; uu < 2; ++uu){
      const int u = w + uu*16;
      if (u < 30){
        const int m = u >> 1, nf = u & 1;
        f32x4 as = (f32x4)0.0f, ak = (f32x4)0.0f;
        const int nrow = h*32 + nf*16 + l15;
        for (int ks = 0; ks < 4; ++ks){
          short8 a2 = ldA(lds, R2, m*16 + l15, ks*4 + l4);
          short8 a1 = ldA(lds, R1, m*16 + l15, ks*4 + l4);
          short8 bs = *(const short8*)(WselB + (size_t)nrow*128 + ks*32 + l4*8);
          short8 bk = *(const short8*)(WkB   + (size_t)nrow*128 + ks*32 + l4*8);
          as = MFMA(a2, bs, as);
          ak = MFMA(a1, bk, ak);
        }
        #pragma unroll
        for (int q = 0; q < 4; ++q){
          int row = m*16 + l4*4 + q, col = nf*16 + l15;
          *(u16*)(lds + P2 + row*64 + col*2) = f2bf(as[q]);
          *(u16*)(lds + P1 + row*64 + col*2) = f2bf(ak[q]);
        }
      }
    }
    __syncthreads();
    // b: logits + softmax (wave w = query agent; 4 lanes per (i,b) unit)
    if (w < 15){
      const int bq = lane >> 2, l = lane & 3;
      const int qrow = w*16 + bq;
      short8 s8 = *(const short8*)(lds + P2 + qrow*64 + l*16);
      float sf[8];
      #pragma unroll
      for (int x = 0; x < 8; ++x) sf[x] = bf2f(s8[x]);
      #pragma unroll
      for (int j = 0; j < 15; ++j){
        short8 k8 = *(const short8*)(lds + P1 + (j*16 + bq)*64 + l*16);
        float d = 0.f;
        #pragma unroll
        for (int x = 0; x < 8; ++x) d += bf2f(k8[x]) * sf[x];
        d += __shfl_xor(d, 1);
        d += __shfl_xor(d, 2);
        pb[j] = d * 0.17677669529663687f;
      }
      float mx = -1e30f;
      #pragma unroll
      for (int j = 0; j < 15; ++j) if (j != w) mx = fmaxf(mx, pb[j]);
      float sum = 0.f;
      #pragma unroll
      for (int j = 0; j < 15; ++j){
        float p = (j == w) ? 0.f : __expf(pb[j] - mx);
        pb[j] = p; sum += p;
      }
      inv = 1.f / sum;
    }
    __syncthreads();
    // c: V_h -> P2 (over sel, dead)
    #pragma unroll
    for (int uu = 0; uu < 2; ++uu){
      const int u = w + uu*16;
      if (u < 30){
        const int m = u >> 1, nf = u & 1;
        f32x4 av = (f32x4)0.0f;
        const int nrow = h*32 + nf*16 + l15;
        for (int ks = 0; ks < 4; ++ks){
          short8 a1 = ldA(lds, R1, m*16 + l15, ks*4 + l4);
          short8 b8 = *(const short8*)(WvB + (size_t)nrow*128 + ks*32 + l4*8);
          av = MFMA(a1, b8, av);
        }
        int col = nf*16 + l15;
        float bb = bvp[h*32 + col];
        #pragma unroll
        for (int q = 0; q < 4; ++q){
          int row = m*16 + l4*4 + q;
          float v = av[q] + bb; v = v > 0.f ? v : 0.01f*v;
          *(u16*)(lds + P2 + row*64 + col*2) = f2bf(v);
        }
      }
    }
    __syncthreads();
    // d: PV (probs @ V) -> attn slice -> P1 (over K, dead)
    // e: acc_c1 += attn_h @ Wc1[128+32h,:]  — same-wave P1 RAW, no barrier needed
    if (w < 15){
      const int bq = lane >> 2, l = lane & 3;
      const int qrow = w*16 + bq;
      float oa[8];
      #pragma unroll
      for (int x = 0; x < 8; ++x) oa[x] = 0.f;
      #pragma unroll
      for (int j = 0; j < 15; ++j){
        if (j == w) continue;
        float p = pb[j];
        short8 v8 = *(const short8*)(lds + P2 + (j*16 + bq)*64 + l*16);
        #pragma unroll
        for (int x = 0; x < 8; ++x) oa[x] += p * bf2f(v8[x]);
      }
      short8 o;
      #pragma unroll
      for (int x = 0; x < 8; ++x) o[x] = (short)f2bf(oa[x] * inv);
      *(short8*)(lds + P1 + qrow*64 + l*16) = o;

      short8 a8 = *(const short8*)(lds + P1 + (w*16 + l15)*64 + l4*16);
      #pragma unroll
      for (int fn = 0; fn < 8; ++fn){
        short8 b8 = *(const short8*)(Wc1B + (size_t)w*32768 + (fn*16 + l15)*256 + 128 + h*32 + l4*8);
        c1[fn] = MFMA(a8, b8, c1[fn]);
      }
    }
    __syncthreads();
  }

  // ---- critic hidden: bias+lrelu -> R2 (over SE, dead) ----
  if (w < 15){
    #pragma unroll
    for (int fn = 0; fn < 8; ++fn){
      int col = fn*16 + l15;
      float bb = bc1[w*128 + col];
      #pragma unroll
      for (int q = 0; q < 4; ++q){
        int row = w*16 + l4*4 + q;
        float v = c1[fn][q] + bb; v = v > 0.f ? v : 0.01f*v;
        stSwz(lds, R2, row, col, f2bf(v));
      }
    }
  }
  __syncthreads();

  // ---- critic GEMM2: out = h @ Wc2 + bc2 -> R3 f32 bounce ----
  #pragma unroll
  for (int uu = 0; uu < 2; ++uu){
    const int u = w + uu*16;
    if (u < 30){
      const int m = u >> 1, nf = u & 1;
      f32x4 a2 = (f32x4)0.0f;
      for (int ks = 0; ks < 4; ++ks){
        short8 a8 = ldA(lds, R2, m*16 + l15, ks*4 + l4);
        short8 b8 = *(const short8*)(Wc2B + (size_t)m*4096 + (nf*16 + l15)*128 + ks*32 + l4*8);
        a2 = MFMA(a8, b8, a2);
      }
      int col = nf*16 + l15;
      float bb = bc2[m*32 + col];
      #pragma unroll
      for (int q = 0; q < 4; ++q){
        int row = m*16 + l4*4 + q;
        *(float*)(lds + R3 + row*128 + col*4) = a2[q] + bb;
      }
    }
  }
  __syncthreads();
  // coalesced copy out
  for (int e = t; e < 1920; e += 1024){
    f32x4 v = *(const f32x4*)(lds + R3 + e*16);
    int row = e >> 3, c4 = e & 7;
    *(f32x4*)(outp + ((size_t)(row >> 4)*NB + b0 + (row & 15))*32 + c4*4) = v;
  }
}

// ---------------- launch ----------------
extern "C" void kernel_launch(void* const* d_in, const int* in_sizes, int n_in,
                              void* d_out, int out_size, void* d_ws, size_t ws_size,
                              hipStream_t stream)
{
  const float* states  = (const float*)d_in[0];
  const float* actions = (const float*)d_in[1];
  const float* Wenc    = (const float*)d_in[2];
  const float* benc    = (const float*)d_in[3];
  const float* Wsenc   = (const float*)d_in[4];
  const float* bsenc   = (const float*)d_in[5];
  const float* Wk      = (const float*)d_in[6];
  const float* Wsel    = (const float*)d_in[7];
  const float* Wv      = (const float*)d_in[8];
  const float* bv      = (const float*)d_in[9];
  const float* Wc1     = (const float*)d_in[10];
  const float* bc1     = (const float*)d_in[11];
  const float* Wc2     = (const float*)d_in[12];
  const float* bc2     = (const float*)d_in[13];

  char* ws = (char*)d_ws;
  u16* WencB  = (u16*)(ws + 0);
  u16* WsencB = (u16*)(ws + 614400);
  u16* WkB    = (u16*)(ws + 1105920);
  u16* WvB    = (u16*)(ws + 1138688);
  u16* WselB  = (u16*)(ws + 1171456);
  u16* Wc1B   = (u16*)(ws + 1204224);
  u16* Wc2B   = (u16*)(ws + 2187264);
  if (ws_size < 2310144ULL) return;

  hipFuncSetAttribute((const void*)k_fused, hipFuncAttributeMaxDynamicSharedMemorySize, K_LDS);

  k0_conv<<<4512, 256, 0, stream>>>(Wenc, Wsenc, Wk, Wsel, Wv, Wc1, Wc2,
                                    WencB, WsencB, WkB, WvB, WselB, Wc1B, Wc2B);
  k_fused<<<2048, 1024, K_LDS, stream>>>(states, actions, benc, bsenc, bv, bc1, bc2,
                                         WencB, WsencB, WkB, WvB, WselB, Wc1B, Wc2B,
                                         (float*)d_out);
}